// Round 2
// baseline (160.715 us; speedup 1.0000x reference)
//
#include <hip/hip_runtime.h>
#include <hip/hip_cooperative_groups.h>
#include <hip/hip_bf16.h>
#include <math.h>

#define B_ROWS 16384
#define C_COLS 1000
#define C_PAD  1024
#define FDIM   1024
#define FBLKS  4096           // feature normalize blocks (4 rows each)
#define FP8_SCALE 256.0f      // pre-scale before e4m3 quant (avoids subnormals)
#define INV_SIM   (1.0f / (FP8_SCALE * FP8_SCALE))

typedef __attribute__((ext_vector_type(8))) short bf16x8;
typedef __attribute__((ext_vector_type(4))) float f32x4;
typedef __attribute__((ext_vector_type(4))) int   i32x4;
typedef __attribute__((ext_vector_type(8))) int   i32x8;

// async global->LDS, 16B per lane; lds dst is wave-uniform base (HW puts lane i at base + i*16)
#define GLD_LDS(gp, lp) __builtin_amdgcn_global_load_lds( \
    (__attribute__((address_space(1))) void*)(gp),        \
    (__attribute__((address_space(3))) void*)(lp), 16, 0, 0)

// ---------------- fused row L2-normalize fp32 -> fp8 e4m3 (x256), one wave per row ---------
__global__ __launch_bounds__(256) void normalize_all(
    const float* __restrict__ feat, const float* __restrict__ prot,
    unsigned char* __restrict__ fb, unsigned char* __restrict__ pb,
    float* __restrict__ rowsum)
{
    const int lane = threadIdx.x & 63;
    const int wave = threadIdx.x >> 6;

    // fold rowsum zeroing into the first 64 blocks (replaces the memset dispatch)
    if (blockIdx.x < 64) rowsum[blockIdx.x * 256 + threadIdx.x] = 0.0f;

    const float* in;
    unsigned char* out;
    int row, nvalid;
    if (blockIdx.x < FBLKS) {
        row = blockIdx.x * 4 + wave;  in = feat; out = fb; nvalid = B_ROWS;
    } else {
        row = (blockIdx.x - FBLKS) * 4 + wave;  in = prot; out = pb; nvalid = C_COLS;
    }
    unsigned char* orow = out + (size_t)row * FDIM;

    if (row >= nvalid) {               // zero-pad prototype rows 1000..1023
        i32x4 z = {0, 0, 0, 0};
        ((i32x4*)orow)[lane] = z;      // 64 lanes x 16 B = 1024 B row
        return;
    }

    // lane owns 16 contiguous elements -> one 16 B fp8 store
    const float4* rp = (const float4*)(in + (size_t)row * FDIM);
    float4 v[4];
    float ss = 0.0f;
    #pragma unroll
    for (int c = 0; c < 4; ++c) {
        v[c] = rp[lane * 4 + c];
        ss += v[c].x * v[c].x + v[c].y * v[c].y + v[c].z * v[c].z + v[c].w * v[c].w;
    }
    #pragma unroll
    for (int off = 1; off < 64; off <<= 1) ss += __shfl_xor(ss, off, 64);
    const float inv = FP8_SCALE / sqrtf(fmaxf(ss, 1e-24f));

    i32x4 pk;
    #pragma unroll
    for (int c = 0; c < 4; ++c) {
        int w0 = __builtin_amdgcn_cvt_pk_fp8_f32(v[c].x * inv, v[c].y * inv, 0, false);
        w0     = __builtin_amdgcn_cvt_pk_fp8_f32(v[c].z * inv, v[c].w * inv, w0, true);
        pk[c] = w0;
    }
    ((i32x4*)orow)[lane] = pk;
}

// ---------------- cooperative MX-fp8 GEMM 128x128 + distance + grid.sync + final write -----
// Distances stay in acc[4][4] registers across the grid barrier; D matrix eliminated.
// Requires 4 blocks/CU co-residency (checked at launch; falls back if not met).
__global__ __launch_bounds__(256, 4) void gemm_dist_out(
    const unsigned char* __restrict__ A,
    const unsigned char* __restrict__ Bp,
    float* __restrict__ rowsum,
    const float* __restrict__ scale,
    const float* __restrict__ temp,
    float* __restrict__ out)
{
    __shared__ unsigned char As[128 * 128];   // 16 KB
    __shared__ unsigned char Bs[128 * 128];   // 16 KB

    const int tid  = threadIdx.x;
    const int lane = tid & 63;
    const int wave = tid >> 6;

    // XCD swizzle: the 8 bn-blocks of one bm share id%8 (same XCD) for A-tile L2 reuse
    const int id  = blockIdx.x;             // 0..1023
    const int xcd = id & 7;
    const int seq = id >> 3;                // 0..127
    const int bn  = seq & 7;                // 0..7
    const int bm  = xcd * 16 + (seq >> 3);  // 0..127

    const int waveM = (wave >> 1) * 64;
    const int waveN = (wave & 1) * 64;

    f32x4 acc[4][4] = {};

    // staging: round r covers rows [r*32, r*32+32); wave w -> rows r*32+w*8 .. +8
    // lane i -> row +(i>>3), phys granule i&7, fetching logical granule (i&7)^(i>>3)
    const int srow8 = lane >> 3;
    const int sg    = (lane & 7) ^ srow8;
    const unsigned char* Abase = A  + ((size_t)(bm * 128 + wave * 8 + srow8)) * FDIM + sg * 16;
    const unsigned char* Bbase = Bp + ((size_t)(bn * 128 + wave * 8 + srow8)) * FDIM + sg * 16;

    // frag addressing: R = waveX + mt*16 + (lane&15); R&7 = lane&7.
    // logical granules for this lane: 2q, 2q+1 (q = lane>>4); phys = g ^ (lane&7)
    const int q2   = (lane >> 4) * 2;
    const int bxor = lane & 7;
    const int fA = (waveM + (lane & 15)) * 128;
    const int fB = (waveN + (lane & 15)) * 128;
    const int pg0 = ((q2)     ^ bxor) * 16;
    const int pg1 = ((q2 + 1) ^ bxor) * 16;

    #pragma unroll 1
    for (int k0 = 0; k0 < FDIM; k0 += 128) {
        __syncthreads();
        #pragma unroll
        for (int r = 0; r < 4; ++r) {
            GLD_LDS(Abase + (size_t)(r * 32) * FDIM + k0, &As[(r * 32 + wave * 8) * 128]);
            GLD_LDS(Bbase + (size_t)(r * 32) * FDIM + k0, &Bs[(r * 32 + wave * 8) * 128]);
        }
        __syncthreads();

        i32x8 b[4];
        #pragma unroll
        for (int nt = 0; nt < 4; ++nt) {
            const i32x4 lo = *(const i32x4*)&Bs[fB + nt * 2048 + pg0];
            const i32x4 hi = *(const i32x4*)&Bs[fB + nt * 2048 + pg1];
            b[nt] = (i32x8){lo.x, lo.y, lo.z, lo.w, hi.x, hi.y, hi.z, hi.w};
        }
        #pragma unroll
        for (int mt = 0; mt < 4; ++mt) {
            const i32x4 lo = *(const i32x4*)&As[fA + mt * 2048 + pg0];
            const i32x4 hi = *(const i32x4*)&As[fA + mt * 2048 + pg1];
            const i32x8 a = (i32x8){lo.x, lo.y, lo.z, lo.w, hi.x, hi.y, hi.z, hi.w};
            #pragma unroll
            for (int nt = 0; nt < 4; ++nt)
                acc[mt][nt] = __builtin_amdgcn_mfma_scale_f32_16x16x128_f8f6f4(
                    a, b[nt], acc[mt][nt], 0, 0, /*opsel_a*/0, /*scale_a*/127, /*opsel_b*/0, /*scale_b*/127);
        }
    }

    // phase 1 epilogue: sim = acc/65536; d = sqrt(max(1-sim,0)) kept IN acc (fp32, no D store)
    // C/D layout: col=lane&15, row=(lane>>4)*4+reg
    const int row0 = bm * 128 + waveM;
    const int col0 = bn * 128 + waveN;
    #pragma unroll
    for (int mt = 0; mt < 4; ++mt) {
        #pragma unroll
        for (int r = 0; r < 4; ++r) {
            float part = 0.0f;
            #pragma unroll
            for (int nt = 0; nt < 4; ++nt) {
                const float sim = acc[mt][nt][r] * INV_SIM;
                const float dv = sqrtf(fmaxf(1.0f - sim, 0.0f));
                acc[mt][nt][r] = dv;
                const int col = col0 + nt * 16 + (lane & 15);
                if (col < C_COLS) part += dv;
            }
            part += __shfl_xor(part, 1, 64);
            part += __shfl_xor(part, 2, 64);
            part += __shfl_xor(part, 4, 64);
            part += __shfl_xor(part, 8, 64);
            if ((lane & 15) == 0)
                atomicAdd(&rowsum[row0 + mt * 16 + (lane >> 4) * 4 + r], part);
        }
    }

    // grid-wide barrier: all rowsum atomics complete after this
    cooperative_groups::this_grid().sync();

    // phase 2: out = (-|ds|/T) * (d + rowsum/1000), straight from registers (fp32)
    const float aS = -fabsf(scale[0]) / temp[0];
    #pragma unroll
    for (int mt = 0; mt < 4; ++mt) {
        #pragma unroll
        for (int r = 0; r < 4; ++r) {
            const int row = row0 + mt * 16 + (lane >> 4) * 4 + r;
            // agent-scope load: defeat stale per-XCD L2/L1 for cross-XCD atomic results
            const float m = __hip_atomic_load(&rowsum[row], __ATOMIC_RELAXED,
                                              __HIP_MEMORY_SCOPE_AGENT) * (1.0f / (float)C_COLS);
            #pragma unroll
            for (int nt = 0; nt < 4; ++nt) {
                const int col = col0 + nt * 16 + (lane & 15);
                if (col < C_COLS)
                    out[(size_t)row * C_COLS + col] = aS * (acc[mt][nt][r] + m);
            }
        }
    }
}

// ---------------- fallback path (proven baseline): GEMM -> D bf16 -> finalize --------------
__global__ __launch_bounds__(256) void gemm_dist(
    const unsigned char* __restrict__ A,
    const unsigned char* __restrict__ Bp,
    __hip_bfloat16* __restrict__ D,
    float* __restrict__ rowsum)
{
    __shared__ unsigned char As[128 * 128];
    __shared__ unsigned char Bs[128 * 128];

    const int tid  = threadIdx.x;
    const int lane = tid & 63;
    const int wave = tid >> 6;

    const int id  = blockIdx.x;
    const int xcd = id & 7;
    const int seq = id >> 3;
    const int bn  = seq & 7;
    const int bm  = xcd * 16 + (seq >> 3);

    const int waveM = (wave >> 1) * 64;
    const int waveN = (wave & 1) * 64;

    f32x4 acc[4][4] = {};

    const int srow8 = lane >> 3;
    const int sg    = (lane & 7) ^ srow8;
    const unsigned char* Abase = A  + ((size_t)(bm * 128 + wave * 8 + srow8)) * FDIM + sg * 16;
    const unsigned char* Bbase = Bp + ((size_t)(bn * 128 + wave * 8 + srow8)) * FDIM + sg * 16;

    const int q2   = (lane >> 4) * 2;
    const int bxor = lane & 7;
    const int fA = (waveM + (lane & 15)) * 128;
    const int fB = (waveN + (lane & 15)) * 128;
    const int pg0 = ((q2)     ^ bxor) * 16;
    const int pg1 = ((q2 + 1) ^ bxor) * 16;

    #pragma unroll 1
    for (int k0 = 0; k0 < FDIM; k0 += 128) {
        __syncthreads();
        #pragma unroll
        for (int r = 0; r < 4; ++r) {
            GLD_LDS(Abase + (size_t)(r * 32) * FDIM + k0, &As[(r * 32 + wave * 8) * 128]);
            GLD_LDS(Bbase + (size_t)(r * 32) * FDIM + k0, &Bs[(r * 32 + wave * 8) * 128]);
        }
        __syncthreads();

        i32x8 b[4];
        #pragma unroll
        for (int nt = 0; nt < 4; ++nt) {
            const i32x4 lo = *(const i32x4*)&Bs[fB + nt * 2048 + pg0];
            const i32x4 hi = *(const i32x4*)&Bs[fB + nt * 2048 + pg1];
            b[nt] = (i32x8){lo.x, lo.y, lo.z, lo.w, hi.x, hi.y, hi.z, hi.w};
        }
        #pragma unroll
        for (int mt = 0; mt < 4; ++mt) {
            const i32x4 lo = *(const i32x4*)&As[fA + mt * 2048 + pg0];
            const i32x4 hi = *(const i32x4*)&As[fA + mt * 2048 + pg1];
            const i32x8 a = (i32x8){lo.x, lo.y, lo.z, lo.w, hi.x, hi.y, hi.z, hi.w};
            #pragma unroll
            for (int nt = 0; nt < 4; ++nt)
                acc[mt][nt] = __builtin_amdgcn_mfma_scale_f32_16x16x128_f8f6f4(
                    a, b[nt], acc[mt][nt], 0, 0, 0, 127, 0, 127);
        }
    }

    const int row0 = bm * 128 + waveM;
    const int col0 = bn * 128 + waveN;
    #pragma unroll
    for (int mt = 0; mt < 4; ++mt) {
        #pragma unroll
        for (int r = 0; r < 4; ++r) {
            const int row = row0 + mt * 16 + (lane >> 4) * 4 + r;
            float part = 0.0f;
            #pragma unroll
            for (int nt = 0; nt < 4; ++nt) {
                const int col = col0 + nt * 16 + (lane & 15);
                const float sim = acc[mt][nt][r] * INV_SIM;
                const float dv = sqrtf(fmaxf(1.0f - sim, 0.0f));
                if (col < C_COLS) {
                    D[(size_t)row * C_COLS + col] = __float2bfloat16(dv);
                    part += dv;
                }
            }
            part += __shfl_xor(part, 1, 64);
            part += __shfl_xor(part, 2, 64);
            part += __shfl_xor(part, 4, 64);
            part += __shfl_xor(part, 8, 64);
            if ((lane & 15) == 0) atomicAdd(&rowsum[row], part);
        }
    }
}

__global__ __launch_bounds__(256) void finalize(
    const __hip_bfloat16* __restrict__ D, const float* __restrict__ rowsum,
    const float* __restrict__ scale, const float* __restrict__ temp,
    float* __restrict__ out)
{
    const size_t i = (size_t)blockIdx.x * 256 + threadIdx.x;   // 8-element group
    const float a = -fabsf(scale[0]) / temp[0];
    const int row = (int)((i * 8) / C_COLS);                   // 1000 % 8 == 0, no straddle
    const float m = rowsum[row] * (1.0f / (float)C_COLS);

    const bf16x8 dv = *(const bf16x8*)(D + i * 8);
    const __hip_bfloat16* dp = (const __hip_bfloat16*)&dv;
    float4 o0, o1;
    o0.x = a * (__bfloat162float(dp[0]) + m);
    o0.y = a * (__bfloat162float(dp[1]) + m);
    o0.z = a * (__bfloat162float(dp[2]) + m);
    o0.w = a * (__bfloat162float(dp[3]) + m);
    o1.x = a * (__bfloat162float(dp[4]) + m);
    o1.y = a * (__bfloat162float(dp[5]) + m);
    o1.z = a * (__bfloat162float(dp[6]) + m);
    o1.w = a * (__bfloat162float(dp[7]) + m);
    ((float4*)out)[i * 2]     = o0;
    ((float4*)out)[i * 2 + 1] = o1;
}

extern "C" void kernel_launch(void* const* d_in, const int* in_sizes, int n_in,
                              void* d_out, int out_size, void* d_ws, size_t ws_size,
                              hipStream_t stream)
{
    const float* features = (const float*)d_in[0];   // [16384,1024]
    const float* protos   = (const float*)d_in[1];   // [1000,1024]
    const float* dscale   = (const float*)d_in[2];   // [1]
    const float* temp     = (const float*)d_in[3];   // [1]
    float* out = (float*)d_out;                      // [16384,1000]

    char* ws = (char*)d_ws;
    unsigned char* fb = (unsigned char*)ws;                       // 16,777,216 B
    unsigned char* pb = (unsigned char*)(ws + 16777216);          //  1,048,576 B
    __hip_bfloat16* D = (__hip_bfloat16*)(ws + 17825792);         // 32,768,000 B (fallback only)
    float* rowsum     = (float*)(ws + 50593792);                  //     65,536 B

    normalize_all<<<FBLKS + C_PAD / 4, 256, 0, stream>>>(features, protos, fb, pb, rowsum);

    // decide coop vs fallback ONCE (host-side queries only; capture-safe)
    static int use_coop = -1;
    if (use_coop < 0) {
        int dev = 0;
        (void)hipGetDevice(&dev);
        int coopOK = 0;
        (void)hipDeviceGetAttribute(&coopOK, hipDeviceAttributeCooperativeLaunch, dev);
        int numCU = 0;
        (void)hipDeviceGetAttribute(&numCU, hipDeviceAttributeMultiprocessorCount, dev);
        int maxB = 0;
        hipError_t oe = hipOccupancyMaxActiveBlocksPerMultiprocessor(
            &maxB, reinterpret_cast<const void*>(gemm_dist_out), 256, 0);
        use_coop = (coopOK && oe == hipSuccess && numCU > 0 &&
                    (long)maxB * numCU >= 1024) ? 1 : 0;
    }

    if (use_coop) {
        const unsigned char* gA = fb;
        const unsigned char* gB = pb;
        float* gR = rowsum;
        const float* gS = dscale;
        const float* gT = temp;
        float* gO = out;
        void* kargs[] = { (void*)&gA, (void*)&gB, (void*)&gR,
                          (void*)&gS, (void*)&gT, (void*)&gO };
        hipError_t le = hipLaunchCooperativeKernel(
            reinterpret_cast<const void*>(gemm_dist_out),
            dim3(1024), dim3(256), kargs, 0, stream);
        if (le != hipSuccess) use_coop = 0;   // fall through to proven path
    }
    if (!use_coop) {
        gemm_dist<<<1024, 256, 0, stream>>>(fb, pb, D, rowsum);
        finalize<<<(B_ROWS * C_COLS / 8) / 256, 256, 0, stream>>>(D, rowsum, dscale, temp, out);
    }
}

// Round 3
// 159.000 us; speedup vs baseline: 1.0108x; 1.0108x over previous
//
#include <hip/hip_runtime.h>
#include <hip/hip_cooperative_groups.h>
#include <hip/hip_bf16.h>
#include <math.h>

#define B_ROWS 16384
#define C_COLS 1000
#define C_PAD  1024
#define FDIM   1024
#define FBLKS  4096           // feature normalize blocks (4 rows each)
#define FP8_SCALE 256.0f      // pre-scale before e4m3 quant (avoids subnormals)
#define INV_SIM   (1.0f / (FP8_SCALE * FP8_SCALE))

typedef __attribute__((ext_vector_type(8))) short bf16x8;
typedef __attribute__((ext_vector_type(4))) float f32x4;
typedef __attribute__((ext_vector_type(4))) int   i32x4;
typedef __attribute__((ext_vector_type(8))) int   i32x8;

// async global->LDS, 16B per lane; lds dst is wave-uniform base (HW puts lane i at base + i*16)
#define GLD_LDS(gp, lp) __builtin_amdgcn_global_load_lds( \
    (__attribute__((address_space(1))) void*)(gp),        \
    (__attribute__((address_space(3))) void*)(lp), 16, 0, 0)

static __device__ __forceinline__ unsigned int pack2bf(float a, float b) {
    __hip_bfloat16 ha = __float2bfloat16(a), hb = __float2bfloat16(b);
    unsigned short ua, ub;
    __builtin_memcpy(&ua, &ha, 2);
    __builtin_memcpy(&ub, &hb, 2);
    return (unsigned int)ua | ((unsigned int)ub << 16);
}
static __device__ __forceinline__ float unpackbf(unsigned int w, int hi) {
    unsigned short us = (unsigned short)(hi ? (w >> 16) : (w & 0xffff));
    __hip_bfloat16 h;
    __builtin_memcpy(&h, &us, 2);
    return __bfloat162float(h);
}

// ---------------- fused row L2-normalize fp32 -> fp8 e4m3 (x256), one wave per row ---------
__global__ __launch_bounds__(256) void normalize_all(
    const float* __restrict__ feat, const float* __restrict__ prot,
    unsigned char* __restrict__ fb, unsigned char* __restrict__ pb,
    float* __restrict__ rowsum)
{
    const int lane = threadIdx.x & 63;
    const int wave = threadIdx.x >> 6;

    // fold rowsum zeroing into the first 64 blocks (replaces the memset dispatch)
    if (blockIdx.x < 64) rowsum[blockIdx.x * 256 + threadIdx.x] = 0.0f;

    const float* in;
    unsigned char* out;
    int row, nvalid;
    if (blockIdx.x < FBLKS) {
        row = blockIdx.x * 4 + wave;  in = feat; out = fb; nvalid = B_ROWS;
    } else {
        row = (blockIdx.x - FBLKS) * 4 + wave;  in = prot; out = pb; nvalid = C_COLS;
    }
    unsigned char* orow = out + (size_t)row * FDIM;

    if (row >= nvalid) {               // zero-pad prototype rows 1000..1023
        i32x4 z = {0, 0, 0, 0};
        ((i32x4*)orow)[lane] = z;      // 64 lanes x 16 B = 1024 B row
        return;
    }

    // lane owns 16 contiguous elements -> one 16 B fp8 store
    const float4* rp = (const float4*)(in + (size_t)row * FDIM);
    float4 v[4];
    float ss = 0.0f;
    #pragma unroll
    for (int c = 0; c < 4; ++c) {
        v[c] = rp[lane * 4 + c];
        ss += v[c].x * v[c].x + v[c].y * v[c].y + v[c].z * v[c].z + v[c].w * v[c].w;
    }
    #pragma unroll
    for (int off = 1; off < 64; off <<= 1) ss += __shfl_xor(ss, off, 64);
    const float inv = FP8_SCALE / sqrtf(fmaxf(ss, 1e-24f));

    i32x4 pk;
    #pragma unroll
    for (int c = 0; c < 4; ++c) {
        int w0 = __builtin_amdgcn_cvt_pk_fp8_f32(v[c].x * inv, v[c].y * inv, 0, false);
        w0     = __builtin_amdgcn_cvt_pk_fp8_f32(v[c].z * inv, v[c].w * inv, w0, true);
        pk[c] = w0;
    }
    ((i32x4*)orow)[lane] = pk;
}

// one 128x128x1024 MX-fp8 GEMM tile into ACC (acc stays fp32 sim*65536)
#define GEMM_TILE(BM_, BN_, ACC) do {                                                        \
    const unsigned char* Abase_ = A  + ((size_t)((BM_) * 128 + wave * 8 + srow8)) * FDIM + sg * 16; \
    const unsigned char* Bbase_ = Bp + ((size_t)((BN_) * 128 + wave * 8 + srow8)) * FDIM + sg * 16; \
    _Pragma("unroll 1")                                                                      \
    for (int k0_ = 0; k0_ < FDIM; k0_ += 128) {                                              \
        __syncthreads();                                                                     \
        _Pragma("unroll")                                                                    \
        for (int r_ = 0; r_ < 4; ++r_) {                                                     \
            GLD_LDS(Abase_ + (size_t)(r_ * 32) * FDIM + k0_, &As[(r_ * 32 + wave * 8) * 128]); \
            GLD_LDS(Bbase_ + (size_t)(r_ * 32) * FDIM + k0_, &Bs[(r_ * 32 + wave * 8) * 128]); \
        }                                                                                    \
        __syncthreads();                                                                     \
        i32x8 bfr_[4];                                                                       \
        _Pragma("unroll")                                                                    \
        for (int nt_ = 0; nt_ < 4; ++nt_) {                                                  \
            const i32x4 lo_ = *(const i32x4*)&Bs[fB + nt_ * 2048 + pg0];                     \
            const i32x4 hi_ = *(const i32x4*)&Bs[fB + nt_ * 2048 + pg1];                     \
            bfr_[nt_] = (i32x8){lo_.x, lo_.y, lo_.z, lo_.w, hi_.x, hi_.y, hi_.z, hi_.w};     \
        }                                                                                    \
        _Pragma("unroll")                                                                    \
        for (int mt_ = 0; mt_ < 4; ++mt_) {                                                  \
            const i32x4 lo_ = *(const i32x4*)&As[fA + mt_ * 2048 + pg0];                     \
            const i32x4 hi_ = *(const i32x4*)&As[fA + mt_ * 2048 + pg1];                     \
            const i32x8 a_ = (i32x8){lo_.x, lo_.y, lo_.z, lo_.w, hi_.x, hi_.y, hi_.z, hi_.w};\
            _Pragma("unroll")                                                                \
            for (int nt_ = 0; nt_ < 4; ++nt_)                                                \
                ACC[mt_][nt_] = __builtin_amdgcn_mfma_scale_f32_16x16x128_f8f6f4(            \
                    a_, bfr_[nt_], ACC[mt_][nt_], 0, 0, 0, 127, 0, 127);                     \
        }                                                                                    \
    }                                                                                        \
} while (0)

// ---------------- cooperative 2-tile MX-fp8 GEMM + distance + grid.sync + final write -----
// 512 blocks x 2 output tiles each (id and id+512: same bn/B-panel, bm+8).
// Tile-1 distances packed to bf16 in regs (32 VGPRs) so the live set during GEMM-2 is
// ~165 regs -> 3 waves/SIMD; only 2 blocks/CU needed for co-residency. No D matrix.
__global__ __launch_bounds__(256) void gemm2_dist_out(
    const unsigned char* __restrict__ A,
    const unsigned char* __restrict__ Bp,
    float* __restrict__ rowsum,
    const float* __restrict__ scale,
    const float* __restrict__ temp,
    float* __restrict__ out)
{
    __shared__ unsigned char As[128 * 128];   // 16 KB
    __shared__ unsigned char Bs[128 * 128];   // 16 KB

    const int tid  = threadIdx.x;
    const int lane = tid & 63;
    const int wave = tid >> 6;

    // tile 0: id in [0,512); tile 1: id+512. XCD swizzle as before.
    const int id  = blockIdx.x;             // 0..511
    const int xcd = id & 7;
    const int seq = id >> 3;                // 0..63
    const int bn  = seq & 7;                // 0..7   (same for both tiles)
    const int bm0 = xcd * 16 + (seq >> 3);  // 0..127 (tile 0)
    const int bm1 = bm0 + 8;                //        (tile 1)

    const int waveM = (wave >> 1) * 64;
    const int waveN = (wave & 1) * 64;

    // staging addressing (shared by both tiles)
    const int srow8 = lane >> 3;
    const int sg    = (lane & 7) ^ srow8;
    // frag addressing
    const int q2   = (lane >> 4) * 2;
    const int bxor = lane & 7;
    const int fA = (waveM + (lane & 15)) * 128;
    const int fB = (waveN + (lane & 15)) * 128;
    const int pg0 = ((q2)     ^ bxor) * 16;
    const int pg1 = ((q2 + 1) ^ bxor) * 16;

    const int col0 = bn * 128 + waveN;

    // ---------------- tile 0: GEMM -> distances -> pack to bf16 regs + rowsum atomics -----
    unsigned int pk1[4][4][2];    // 32 VGPRs: (r0,r1),(r2,r3) packed bf16 per (mt,nt)
    {
        f32x4 acc[4][4] = {};
        GEMM_TILE(bm0, bn, acc);

        const int row0 = bm0 * 128 + waveM;
        #pragma unroll
        for (int mt = 0; mt < 4; ++mt) {
            #pragma unroll
            for (int r = 0; r < 4; ++r) {
                float part = 0.0f;
                #pragma unroll
                for (int nt = 0; nt < 4; ++nt) {
                    const float sim = acc[mt][nt][r] * INV_SIM;
                    const float dv = sqrtf(fmaxf(1.0f - sim, 0.0f));
                    acc[mt][nt][r] = dv;
                    const int col = col0 + nt * 16 + (lane & 15);
                    if (col < C_COLS) part += dv;
                }
                part += __shfl_xor(part, 1, 64);
                part += __shfl_xor(part, 2, 64);
                part += __shfl_xor(part, 4, 64);
                part += __shfl_xor(part, 8, 64);
                if ((lane & 15) == 0)
                    atomicAdd(&rowsum[row0 + mt * 16 + (lane >> 4) * 4 + r], part);
            }
            #pragma unroll
            for (int nt = 0; nt < 4; ++nt) {
                pk1[mt][nt][0] = pack2bf(acc[mt][nt][0], acc[mt][nt][1]);
                pk1[mt][nt][1] = pack2bf(acc[mt][nt][2], acc[mt][nt][3]);
            }
        }
    }

    // ---------------- tile 1: GEMM -> distances stay fp32 in acc2 + rowsum atomics --------
    f32x4 acc2[4][4] = {};
    GEMM_TILE(bm1, bn, acc2);
    {
        const int row0 = bm1 * 128 + waveM;
        #pragma unroll
        for (int mt = 0; mt < 4; ++mt) {
            #pragma unroll
            for (int r = 0; r < 4; ++r) {
                float part = 0.0f;
                #pragma unroll
                for (int nt = 0; nt < 4; ++nt) {
                    const float sim = acc2[mt][nt][r] * INV_SIM;
                    const float dv = sqrtf(fmaxf(1.0f - sim, 0.0f));
                    acc2[mt][nt][r] = dv;
                    const int col = col0 + nt * 16 + (lane & 15);
                    if (col < C_COLS) part += dv;
                }
                part += __shfl_xor(part, 1, 64);
                part += __shfl_xor(part, 2, 64);
                part += __shfl_xor(part, 4, 64);
                part += __shfl_xor(part, 8, 64);
                if ((lane & 15) == 0)
                    atomicAdd(&rowsum[row0 + mt * 16 + (lane >> 4) * 4 + r], part);
            }
        }
    }

    // grid-wide barrier: all rowsum atomics complete after this
    cooperative_groups::this_grid().sync();

    // ---------------- phase 2: out = (-|ds|/T) * (d + rowsum/1000) ------------------------
    const float aS = -fabsf(scale[0]) / temp[0];

    // tile 1 from fp32 regs
    #pragma unroll
    for (int mt = 0; mt < 4; ++mt) {
        #pragma unroll
        for (int r = 0; r < 4; ++r) {
            const int row = bm1 * 128 + waveM + mt * 16 + (lane >> 4) * 4 + r;
            const float m = __hip_atomic_load(&rowsum[row], __ATOMIC_RELAXED,
                                              __HIP_MEMORY_SCOPE_AGENT) * (1.0f / (float)C_COLS);
            #pragma unroll
            for (int nt = 0; nt < 4; ++nt) {
                const int col = col0 + nt * 16 + (lane & 15);
                if (col < C_COLS)
                    out[(size_t)row * C_COLS + col] = aS * (acc2[mt][nt][r] + m);
            }
        }
    }
    // tile 0 from packed bf16 regs
    #pragma unroll
    for (int mt = 0; mt < 4; ++mt) {
        #pragma unroll
        for (int r = 0; r < 4; ++r) {
            const int row = bm0 * 128 + waveM + mt * 16 + (lane >> 4) * 4 + r;
            const float m = __hip_atomic_load(&rowsum[row], __ATOMIC_RELAXED,
                                              __HIP_MEMORY_SCOPE_AGENT) * (1.0f / (float)C_COLS);
            #pragma unroll
            for (int nt = 0; nt < 4; ++nt) {
                const int col = col0 + nt * 16 + (lane & 15);
                if (col < C_COLS) {
                    const float dv = unpackbf(pk1[mt][nt][r >> 1], r & 1);
                    out[(size_t)row * C_COLS + col] = aS * (dv + m);
                }
            }
        }
    }
}

// ---------------- fallback path (proven baseline): GEMM -> D bf16 -> finalize --------------
__global__ __launch_bounds__(256) void gemm_dist(
    const unsigned char* __restrict__ A,
    const unsigned char* __restrict__ Bp,
    __hip_bfloat16* __restrict__ D,
    float* __restrict__ rowsum)
{
    __shared__ unsigned char As[128 * 128];
    __shared__ unsigned char Bs[128 * 128];

    const int tid  = threadIdx.x;
    const int lane = tid & 63;
    const int wave = tid >> 6;

    const int id  = blockIdx.x;
    const int xcd = id & 7;
    const int seq = id >> 3;
    const int bn  = seq & 7;
    const int bm  = xcd * 16 + (seq >> 3);

    const int waveM = (wave >> 1) * 64;
    const int waveN = (wave & 1) * 64;

    f32x4 acc[4][4] = {};

    const int srow8 = lane >> 3;
    const int sg    = (lane & 7) ^ srow8;
    const int q2   = (lane >> 4) * 2;
    const int bxor = lane & 7;
    const int fA = (waveM + (lane & 15)) * 128;
    const int fB = (waveN + (lane & 15)) * 128;
    const int pg0 = ((q2)     ^ bxor) * 16;
    const int pg1 = ((q2 + 1) ^ bxor) * 16;

    GEMM_TILE(bm, bn, acc);

    const int row0 = bm * 128 + waveM;
    const int col0 = bn * 128 + waveN;
    #pragma unroll
    for (int mt = 0; mt < 4; ++mt) {
        #pragma unroll
        for (int r = 0; r < 4; ++r) {
            const int row = row0 + mt * 16 + (lane >> 4) * 4 + r;
            float part = 0.0f;
            #pragma unroll
            for (int nt = 0; nt < 4; ++nt) {
                const int col = col0 + nt * 16 + (lane & 15);
                const float sim = acc[mt][nt][r] * INV_SIM;
                const float dv = sqrtf(fmaxf(1.0f - sim, 0.0f));
                if (col < C_COLS) {
                    D[(size_t)row * C_COLS + col] = __float2bfloat16(dv);
                    part += dv;
                }
            }
            part += __shfl_xor(part, 1, 64);
            part += __shfl_xor(part, 2, 64);
            part += __shfl_xor(part, 4, 64);
            part += __shfl_xor(part, 8, 64);
            if ((lane & 15) == 0) atomicAdd(&rowsum[row], part);
        }
    }
}

__global__ __launch_bounds__(256) void finalize(
    const __hip_bfloat16* __restrict__ D, const float* __restrict__ rowsum,
    const float* __restrict__ scale, const float* __restrict__ temp,
    float* __restrict__ out)
{
    const size_t i = (size_t)blockIdx.x * 256 + threadIdx.x;   // 8-element group
    const float a = -fabsf(scale[0]) / temp[0];
    const int row = (int)((i * 8) / C_COLS);                   // 1000 % 8 == 0, no straddle
    const float m = rowsum[row] * (1.0f / (float)C_COLS);

    const bf16x8 dv = *(const bf16x8*)(D + i * 8);
    const __hip_bfloat16* dp = (const __hip_bfloat16*)&dv;
    float4 o0, o1;
    o0.x = a * (__bfloat162float(dp[0]) + m);
    o0.y = a * (__bfloat162float(dp[1]) + m);
    o0.z = a * (__bfloat162float(dp[2]) + m);
    o0.w = a * (__bfloat162float(dp[3]) + m);
    o1.x = a * (__bfloat162float(dp[4]) + m);
    o1.y = a * (__bfloat162float(dp[5]) + m);
    o1.z = a * (__bfloat162float(dp[6]) + m);
    o1.w = a * (__bfloat162float(dp[7]) + m);
    ((float4*)out)[i * 2]     = o0;
    ((float4*)out)[i * 2 + 1] = o1;
}

extern "C" void kernel_launch(void* const* d_in, const int* in_sizes, int n_in,
                              void* d_out, int out_size, void* d_ws, size_t ws_size,
                              hipStream_t stream)
{
    const float* features = (const float*)d_in[0];   // [16384,1024]
    const float* protos   = (const float*)d_in[1];   // [1000,1024]
    const float* dscale   = (const float*)d_in[2];   // [1]
    const float* temp     = (const float*)d_in[3];   // [1]
    float* out = (float*)d_out;                      // [16384,1000]

    char* ws = (char*)d_ws;
    unsigned char* fb = (unsigned char*)ws;                       // 16,777,216 B
    unsigned char* pb = (unsigned char*)(ws + 16777216);          //  1,048,576 B
    __hip_bfloat16* D = (__hip_bfloat16*)(ws + 17825792);         // 32,768,000 B (fallback only)
    float* rowsum     = (float*)(ws + 50593792);                  //     65,536 B

    normalize_all<<<FBLKS + C_PAD / 4, 256, 0, stream>>>(features, protos, fb, pb, rowsum);

    // decide coop vs fallback ONCE (host-side queries only; capture-safe)
    static int use_coop = -1;
    if (use_coop < 0) {
        int dev = 0;
        (void)hipGetDevice(&dev);
        int coopOK = 0;
        (void)hipDeviceGetAttribute(&coopOK, hipDeviceAttributeCooperativeLaunch, dev);
        int numCU = 0;
        (void)hipDeviceGetAttribute(&numCU, hipDeviceAttributeMultiprocessorCount, dev);
        int maxB = 0;
        hipError_t oe = hipOccupancyMaxActiveBlocksPerMultiprocessor(
            &maxB, reinterpret_cast<const void*>(gemm2_dist_out), 256, 0);
        use_coop = (coopOK && oe == hipSuccess && numCU > 0 &&
                    (long)maxB * numCU >= 512) ? 1 : 0;
    }

    if (use_coop) {
        const unsigned char* gA = fb;
        const unsigned char* gB = pb;
        float* gR = rowsum;
        const float* gS = dscale;
        const float* gT = temp;
        float* gO = out;
        void* kargs[] = { (void*)&gA, (void*)&gB, (void*)&gR,
                          (void*)&gS, (void*)&gT, (void*)&gO };
        hipError_t le = hipLaunchCooperativeKernel(
            reinterpret_cast<const void*>(gemm2_dist_out),
            dim3(512), dim3(256), kargs, 0, stream);
        if (le != hipSuccess) use_coop = 0;   // fall through to proven path
    }
    if (!use_coop) {
        gemm_dist<<<1024, 256, 0, stream>>>(fb, pb, D, rowsum);
        finalize<<<(B_ROWS * C_COLS / 8) / 256, 256, 0, stream>>>(D, rowsum, dscale, temp, out);
    }
}